// Round 7
// baseline (278.835 us; speedup 1.0000x reference)
//
#include <hip/hip_runtime.h>

// CQAttention: B=32, Lc=2048, Lq=256, d=128.
// out[b,i,:] = [C, C2Q, C*C2Q, C*Q2C], fp32, 512 wide.
//
// Pipeline (all bf16 MFMA 16x16x32):
//   pre: Qbf (row-major bf16), Qt (Q^T bf16), rq = Q.w_q
//   k1 : E' = exp(S)/l2[i] (softmax axis-2), l2g, l1 (col sums, atomics);
//        writes Ct = C^T bf16, E (row-major) AND Et = E'^T ([b][j][i],
//        packed 8B stores straight from the MFMA accumulator layout —
//        no LDS round-trip). Masking folded into rcs/rqs.
//   k3 : Tt' = (Ct @ E'^T) / l1[j] — LDS-FREE, BARRIER-FREE: A-frags from
//        Ct rows, B-frags from Et rows, all L2-hot under b%8 XCD swizzle.
//        dt==0 blocks also emit Qts = Qt / l1[j].
//   k4 : C2Q = l2[i]*(E'@Qts), Q2C = l2[i]*(E'@Tt'); E' staged once in LDS,
//        B-operands read directly from global (L2-hot), b%8 swizzle.
//
// l2 divides out of axis-1 softmax: S1 = E' * l2[i]/l1[j], so scaling the tiny
// Qt/Tt operands by 1/l1 and the k4 accumulators by l2[i] is exact algebra.
//
// LDS tile rules learned the hard way:
//  - rows read as bf16x8 need 16B-multiple stride (ds_read_b128 alignment);
//  - row STORAGE must hold the full K-chunk (rounds 2-3 shrank a row below
//    128 elems and overflowed into later rows -> garbage).

#define LC 2048
#define LQ 256
#define DM 128
#define NEG_INF_F (-1e30f)

using bf16x8   = __attribute__((ext_vector_type(8))) __bf16;
using f32x4    = __attribute__((ext_vector_type(4))) float;
using ushort8  = __attribute__((ext_vector_type(8))) unsigned short;
using ushort4v = __attribute__((ext_vector_type(4))) unsigned short;

__device__ __forceinline__ unsigned short f2bf(float x) {
    unsigned int u = __float_as_uint(x);
    u += 0x7fffu + ((u >> 16) & 1u);
    return (unsigned short)(u >> 16);
}
__device__ __forceinline__ float bf2f(unsigned short h) {
    return __uint_as_float(((unsigned int)h) << 16);
}
__device__ __forceinline__ f32x4 mfma16(bf16x8 a, bf16x8 b, f32x4 c) {
    return __builtin_amdgcn_mfma_f32_16x16x32_bf16(a, b, c, 0, 0, 0);
}

// ---------------------------------------------------------------------------
// Pre-Q: Qbf row-major bf16, Qt transposed bf16, rq = Q . w_q (atomic partial).
__global__ __launch_bounds__(256) void k_preQ(const float* __restrict__ Q,
        const float* __restrict__ w, unsigned short* __restrict__ Qbf,
        unsigned short* __restrict__ Qt, float* __restrict__ rq) {
    const int b = blockIdx.z, j0 = blockIdx.x * 64, d0 = blockIdx.y * 64;
    const int tid = threadIdx.x;
    __shared__ float tile[64][65];
    __shared__ float wq[128];
    if (tid < 128) wq[tid] = w[tid];
    __syncthreads();
    const int r = tid >> 2, c0 = (tid & 3) * 16;
    const float4* sp = (const float4*)(Q + (size_t)(b * LQ + j0 + r) * DM + d0 + c0);
    float v[16];
#pragma unroll
    for (int u = 0; u < 4; ++u) {
        float4 t = sp[u];
        v[4*u] = t.x; v[4*u+1] = t.y; v[4*u+2] = t.z; v[4*u+3] = t.w;
    }
    unsigned short ob[16];
    float p = 0.f;
#pragma unroll
    for (int u = 0; u < 16; ++u) {
        ob[u] = f2bf(v[u]);
        p += v[u] * wq[d0 + c0 + u];
        tile[r][c0 + u] = v[u];
    }
    ushort8* qb = (ushort8*)(Qbf + (size_t)(b * LQ + j0 + r) * DM + d0 + c0);
    qb[0] = *(ushort8*)&ob[0];
    qb[1] = *(ushort8*)&ob[8];
    p += __shfl_xor(p, 1);
    p += __shfl_xor(p, 2);
    if ((tid & 3) == 0) atomicAdd(&rq[b * LQ + j0 + r], p);
    __syncthreads();
    unsigned short o[16];
#pragma unroll
    for (int u = 0; u < 16; ++u) o[u] = f2bf(tile[c0 + u][r]);
    ushort8* dp = (ushort8*)(Qt + (size_t)(b * DM + d0 + r) * LQ + j0 + c0);
    dp[0] = *(ushort8*)&o[0];
    dp[1] = *(ushort8*)&o[8];
}

// ---------------------------------------------------------------------------
// K1: E' = exp(S)/l2, l2g, l1 atomics, Ct = C^T bf16, E row-major, Et = E'^T.
// grid (32 itiles, 32 b), 256 thr. Tile 64(i) x 256(j); B-fragments read
// directly from global Qbf (L2-hot). Masks folded into rcs/rqs.
__global__ __launch_bounds__(256) void k1_scores(
    const float* __restrict__ C, const unsigned short* __restrict__ Qbf,
    const float* __restrict__ w, const float* __restrict__ bptr,
    const int* __restrict__ c_mask, const int* __restrict__ q_mask,
    const float* __restrict__ rq,
    unsigned short* __restrict__ E, unsigned short* __restrict__ Et,
    unsigned short* __restrict__ Ct,
    float* __restrict__ l1g, float* __restrict__ l2g) {
    const int b = blockIdx.y;
    const int i0 = blockIdx.x * 64;
    const int tid = threadIdx.x;
    const int lane = tid & 63, wid = tid >> 6;
    const int quad = lane >> 4, l15 = lane & 15;

    __shared__ unsigned short Alds[64][136];  // (C*w_m) bf16
    __shared__ float wsm[256];                // [0:128)=w_c, [128:256)=w_m
    __shared__ float rcs[64], rqs[256], l2s[64];

    if (tid < 256) {
        wsm[tid] = w[128 + tid];
        const float qm = (float)q_mask[b * LQ + tid];
        rqs[tid] = (qm != 0.f) ? (rq[b * LQ + tid] + bptr[0]) : NEG_INF_F;
    }
    if (tid < 64) l2s[tid] = 0.f;
    __syncthreads();

    {   // stage A = C*w_m (bf16), rc = C . w_c (mask-folded), emit Ct = C^T
        const int r = tid >> 2, qq = tid & 3;
        const float4* cp = (const float4*)(C + (size_t)(b * LC + i0 + r) * DM + qq * 32);
        unsigned short* ctb = Ct + (size_t)b * DM * LC + i0 + r;
        float prc = 0.f;
#pragma unroll
        for (int u = 0; u < 8; ++u) {
            float4 v = cp[u];
            const int c0 = qq * 32 + u * 4;
            prc += v.x * wsm[c0] + v.y * wsm[c0 + 1] + v.z * wsm[c0 + 2] + v.w * wsm[c0 + 3];
            Alds[r][c0 + 0] = f2bf(v.x * wsm[128 + c0]);
            Alds[r][c0 + 1] = f2bf(v.y * wsm[129 + c0]);
            Alds[r][c0 + 2] = f2bf(v.z * wsm[130 + c0]);
            Alds[r][c0 + 3] = f2bf(v.w * wsm[131 + c0]);
            ctb[(size_t)(c0 + 0) * LC] = f2bf(v.x);
            ctb[(size_t)(c0 + 1) * LC] = f2bf(v.y);
            ctb[(size_t)(c0 + 2) * LC] = f2bf(v.z);
            ctb[(size_t)(c0 + 3) * LC] = f2bf(v.w);
        }
        prc += __shfl_xor(prc, 1);
        prc += __shfl_xor(prc, 2);
        if (qq == 0) {
            const float cmv = (float)c_mask[b * LC + i0 + r];
            rcs[r] = (cmv != 0.f) ? prc : NEG_INF_F;
        }
    }
    __syncthreads();

    const int n_base = wid * 64;
    const unsigned short* qbase = Qbf + (size_t)b * LQ * DM;
    const f32x4 z4 = {0.f, 0.f, 0.f, 0.f};
    f32x4 acc[4][4];
#pragma unroll
    for (int mt = 0; mt < 4; ++mt)
#pragma unroll
        for (int nt = 0; nt < 4; ++nt) acc[mt][nt] = z4;

#pragma unroll
    for (int kc = 0; kc < 4; ++kc) {
        const int ko = kc * 32 + quad * 8;
        bf16x8 af[4], bfr[4];
#pragma unroll
        for (int mt = 0; mt < 4; ++mt)
            af[mt] = *(const bf16x8*)&Alds[mt * 16 + l15][ko];
#pragma unroll
        for (int nt = 0; nt < 4; ++nt)
            bfr[nt] = *(const bf16x8*)(qbase + (size_t)(n_base + nt * 16 + l15) * DM + ko);
#pragma unroll
        for (int mt = 0; mt < 4; ++mt)
#pragma unroll
            for (int nt = 0; nt < 4; ++nt)
                acc[mt][nt] = mfma16(af[mt], bfr[nt], acc[mt][nt]);
    }

    float colsum[4] = {0.f, 0.f, 0.f, 0.f};
#pragma unroll
    for (int mt = 0; mt < 4; ++mt) {
#pragma unroll
        for (int reg = 0; reg < 4; ++reg) {
            const int m = mt * 16 + quad * 4 + reg;
            float rowsum = 0.f;
#pragma unroll
            for (int nt = 0; nt < 4; ++nt) {
                const int n = n_base + nt * 16 + l15;
                const float s = acc[mt][nt][reg] + rcs[m] + rqs[n];
                const float e = __expf(s);
                acc[mt][nt][reg] = e;      // keep raw e in regs
                rowsum += e;
                colsum[nt] += e;
            }
            rowsum += __shfl_xor(rowsum, 1);
            rowsum += __shfl_xor(rowsum, 2);
            rowsum += __shfl_xor(rowsum, 4);
            rowsum += __shfl_xor(rowsum, 8);
            if (l15 == 0) atomicAdd(&l2s[m], rowsum);
        }
    }
#pragma unroll
    for (int nt = 0; nt < 4; ++nt) {
        float v = colsum[nt];
        v += __shfl_xor(v, 16);
        v += __shfl_xor(v, 32);
        if (quad == 0) atomicAdd(&l1g[b * LQ + n_base + nt * 16 + l15], v);
    }
    __syncthreads();
    if (tid < 64) l2g[b * LC + i0 + tid] = l2s[tid];

    // Epilogue: E row-major (scalar 2B, 32B/16-lane-group) + Et = E'^T
    // (packed 8B stores straight from the accumulator: reg 0..3 are 4
    //  consecutive i for fixed j -> one ushort4; 16 rows x 32B per instr).
#pragma unroll
    for (int mt = 0; mt < 4; ++mt) {
        float rl4[4];
#pragma unroll
        for (int reg = 0; reg < 4; ++reg)
            rl4[reg] = 1.0f / l2s[mt * 16 + quad * 4 + reg];
#pragma unroll
        for (int reg = 0; reg < 4; ++reg) {
            const int m = mt * 16 + quad * 4 + reg;
            unsigned short* erow = E + (size_t)(b * LC + i0 + m) * LQ;
#pragma unroll
            for (int nt = 0; nt < 4; ++nt) {
                const int n = n_base + nt * 16 + l15;
                erow[n] = f2bf(acc[mt][nt][reg] * rl4[reg]);
            }
        }
#pragma unroll
        for (int nt = 0; nt < 4; ++nt) {
            const int j = n_base + nt * 16 + l15;
            unsigned short o4[4];
#pragma unroll
            for (int reg = 0; reg < 4; ++reg)
                o4[reg] = f2bf(acc[mt][nt][reg] * rl4[reg]);
            *(ushort4v*)(Et + (size_t)(b * LQ + j) * LC + i0 + mt * 16 + quad * 4)
                = *(ushort4v*)o4;
        }
    }
}

// ---------------------------------------------------------------------------
// K3: Tt'[d][j] = (sum_i Ct[d][i]*E'[i][j]) / l1[j]. 1D grid 256 blocks,
// 512 thr (8 waves), tile 64(d) x 64(j), K=2048 streamed 32 at a time.
// LDS-free, barrier-free main loop: A-frags from Ct rows, B-frags from Et
// rows — all L2-resident (b%8 XCD swizzle keeps same-b blocks on one XCD).
// dt==0 blocks also emit Qts = Qt / l1[j] for their j-range.
__global__ __launch_bounds__(512) void k3_Tt(
    const unsigned short* __restrict__ Et, const unsigned short* __restrict__ Ct,
    const unsigned short* __restrict__ Qt, const float* __restrict__ l1g,
    unsigned short* __restrict__ Qts, unsigned short* __restrict__ Tt) {
    const int id = blockIdx.x;
    const int t = id >> 3;
    const int jt = t & 3, dt = (t >> 2) & 1;
    const int b = ((t >> 3) << 3) | (id & 7);
    const int j0 = jt * 64, d0 = dt * 64;
    const int tid = threadIdx.x;
    const int lane = tid & 63, wid = tid >> 6;
    const int quad = lane >> 4, l15 = lane & 15;
    const int m_base = (wid >> 1) * 16, n32 = (wid & 1) * 32;

    __shared__ float rl1s[64];
    if (tid < 64) rl1s[tid] = 1.0f / l1g[b * LQ + j0 + tid];
    __syncthreads();

    if (dt == 0) {   // kS fold: Qts = Qt / l1 over [128 d][j0..j0+64)
        const int r = tid >> 2, jq = (tid & 3) * 16;
        const ushort8* qp = (const ushort8*)(Qt + (size_t)(b * DM + r) * LQ + j0 + jq);
        ushort8 v0 = qp[0], v1 = qp[1];
        unsigned short o[16];
#pragma unroll
        for (int u = 0; u < 8; ++u) o[u] = f2bf(bf2f(v0[u]) * rl1s[jq + u]);
#pragma unroll
        for (int u = 0; u < 8; ++u) o[8 + u] = f2bf(bf2f(v1[u]) * rl1s[jq + 8 + u]);
        ushort8* op = (ushort8*)(Qts + (size_t)(b * DM + r) * LQ + j0 + jq);
        op[0] = *(ushort8*)&o[0];
        op[1] = *(ushort8*)&o[8];
    }

    const unsigned short* arow  = Ct + (size_t)(b * DM + d0 + m_base + l15) * LC + quad * 8;
    const unsigned short* brow0 = Et + (size_t)(b * LQ + j0 + n32 + l15) * LC + quad * 8;
    const unsigned short* brow1 = Et + (size_t)(b * LQ + j0 + n32 + 16 + l15) * LC + quad * 8;

    const f32x4 z4 = {0.f, 0.f, 0.f, 0.f};
    f32x4 acc[2] = {z4, z4};

#pragma unroll 4
    for (int kc = 0; kc < 64; ++kc) {
        const int ko = kc * 32;
        bf16x8 af  = *(const bf16x8*)(arow + ko);
        bf16x8 b0f = *(const bf16x8*)(brow0 + ko);
        bf16x8 b1f = *(const bf16x8*)(brow1 + ko);
        acc[0] = mfma16(af, b0f, acc[0]);
        acc[1] = mfma16(af, b1f, acc[1]);
    }

#pragma unroll
    for (int nt = 0; nt < 2; ++nt)
#pragma unroll
        for (int reg = 0; reg < 4; ++reg) {
            const int dd = d0 + m_base + quad * 4 + reg;
            const int jl = n32 + nt * 16 + l15;
            Tt[(size_t)(b * DM + dd) * LQ + j0 + jl] = f2bf(acc[nt][reg] * rl1s[jl]);
        }
}

// ---------------------------------------------------------------------------
// K4: acc1 = E'@Qts, acc2 = E'@Tt'; out = [C, l2*acc1, C*l2*acc1, C*l2*acc2].
// 1D grid 1024 blocks (b%8 XCD class matches k3's), 256 thr (4 waves),
// tile 64(i) x 128(d). E' staged once in LDS (one barrier); Qts/Tt B-frags
// read directly from global (L2-hot).
__global__ __launch_bounds__(256) void k4_out(
    const unsigned short* __restrict__ E, const float* __restrict__ C,
    const unsigned short* __restrict__ Qts, const unsigned short* __restrict__ Tt,
    const float* __restrict__ l2g, float* __restrict__ out) {
    const int id = blockIdx.x;
    const int b = (id & 7) | ((id >> 8) << 3);
    const int i0 = ((id >> 3) & 31) * 64;
    const int tid = threadIdx.x;
    const int lane = tid & 63, wid = tid >> 6;
    const int quad = lane >> 4, l15 = lane & 15;
    const int n_base = wid * 32;

    __shared__ unsigned short Aq[64][264];   // E' full-j tile (256 + 8 pad)
    __shared__ float l2s[64];
    if (tid < 64) l2s[tid] = l2g[b * LC + i0 + tid];

    {   // stage E' tile (64 rows x 256 j), coalesced, once
        const int r = tid >> 2, c0 = (tid & 3) * 64;
        const ushort8* ep = (const ushort8*)(E + (size_t)(b * LC + i0 + r) * LQ + c0);
#pragma unroll
        for (int u = 0; u < 8; ++u) *(ushort8*)&Aq[r][c0 + u * 8] = ep[u];
    }
    __syncthreads();

    const unsigned short* qsb = Qts + (size_t)b * DM * LQ;
    const unsigned short* ttb = Tt  + (size_t)b * DM * LQ;
    const f32x4 z4 = {0.f, 0.f, 0.f, 0.f};
    f32x4 acc1[4][2], acc2[4][2];
#pragma unroll
    for (int mt = 0; mt < 4; ++mt)
#pragma unroll
        for (int nt = 0; nt < 2; ++nt) { acc1[mt][nt] = z4; acc2[mt][nt] = z4; }

#pragma unroll 2
    for (int ks = 0; ks < 8; ++ks) {
        const int ko = ks * 32 + quad * 8;
        bf16x8 a[4], bq[2], bt[2];
#pragma unroll
        for (int mt = 0; mt < 4; ++mt)
            a[mt] = *(const bf16x8*)&Aq[mt * 16 + l15][ko];
#pragma unroll
        for (int nt = 0; nt < 2; ++nt) {
            const size_t roff = (size_t)(n_base + nt * 16 + l15) * LQ + ko;
            bq[nt] = *(const bf16x8*)(qsb + roff);
            bt[nt] = *(const bf16x8*)(ttb + roff);
        }
#pragma unroll
        for (int mt = 0; mt < 4; ++mt)
#pragma unroll
            for (int nt = 0; nt < 2; ++nt) {
                acc1[mt][nt] = mfma16(a[mt], bq[nt], acc1[mt][nt]);
                acc2[mt][nt] = mfma16(a[mt], bt[nt], acc2[mt][nt]);
            }
    }

#pragma unroll
    for (int mt = 0; mt < 4; ++mt)
#pragma unroll
        for (int reg = 0; reg < 4; ++reg) {
            const int il = mt * 16 + quad * 4 + reg;
            const int i = i0 + il;
            const float l2v = l2s[il];
            const size_t rb = (size_t)(b * LC + i) * 512;
            const float* crow = C + (size_t)(b * LC + i) * DM;
#pragma unroll
            for (int nt = 0; nt < 2; ++nt) {
                const int d = n_base + nt * 16 + l15;
                const float c = crow[d];
                const float v1 = acc1[mt][nt][reg] * l2v;
                const float v2 = acc2[mt][nt][reg] * l2v;
                out[rb + d] = c;
                out[rb + 128 + d] = v1;
                out[rb + 256 + d] = c * v1;
                out[rb + 384 + d] = c * v2;
            }
        }
}

// ---------------------------------------------------------------------------
extern "C" void kernel_launch(void* const* d_in, const int* in_sizes, int n_in,
                              void* d_out, int out_size, void* d_ws, size_t ws_size,
                              hipStream_t stream) {
    const float* C = (const float*)d_in[0];
    const float* Q = (const float*)d_in[1];
    const float* w = (const float*)d_in[2];
    const float* bp = (const float*)d_in[3];
    const int* cm = (const int*)d_in[4];
    const int* qm = (const int*)d_in[5];
    float* out = (float*)d_out;

    char* ws = (char*)d_ws;
    // E 32MB | Ct 16MB | Qbf 2MB | Qt 2MB | Qts 2MB | Tt 2MB | l2g 256KB |
    // rq 32KB | l1 32KB | Et 32MB
    unsigned short* E   = (unsigned short*)(ws);
    unsigned short* Ct  = (unsigned short*)(ws + 33554432);
    unsigned short* Qbf = (unsigned short*)(ws + 50331648);
    unsigned short* Qt  = (unsigned short*)(ws + 52428800);
    unsigned short* Qts = (unsigned short*)(ws + 54525952);
    unsigned short* Tt  = (unsigned short*)(ws + 56623104);
    float*          l2g = (float*)(ws + 58720256);
    float*          rq  = (float*)(ws + 58982400);
    float*          l1  = (float*)(ws + 59015168);
    unsigned short* Et  = (unsigned short*)(ws + 59047936);

    hipMemsetAsync(ws + 58982400, 0, 65536, stream);  // zero rq + l1

    k_preQ<<<dim3(4, 2, 32), 256, 0, stream>>>(Q, w, Qbf, Qt, rq);
    k1_scores<<<dim3(32, 32), 256, 0, stream>>>(C, Qbf, w, bp, cm, qm, rq, E, Et, Ct, l1, l2g);
    k3_Tt<<<dim3(256), 512, 0, stream>>>(Et, Ct, Qt, l1, Qts, Tt);
    k4_out<<<dim3(1024), 256, 0, stream>>>(E, C, Qts, Tt, l2g, out);
}

// Round 8
// 240.194 us; speedup vs baseline: 1.1609x; 1.1609x over previous
//
#include <hip/hip_runtime.h>

// CQAttention: B=32, Lc=2048, Lq=256, d=128.
// out[b,i,:] = [C, C2Q, C*C2Q, C*Q2C], fp32, 512 wide.
//
// Pipeline (all bf16 MFMA 16x16x32):
//   pre: Qbf (row-major bf16), Qt (Q^T bf16), rq = Q.w_q
//   k1 : E' = exp(S)/l2[i] (softmax axis-2), l2g, l1 (col sums, atomics);
//        also writes Ct = C^T bf16. Masking folded into rcs/rqs.
//   k3 : Tt' = (Ct @ E'^T) / l1[j]; 512 blocks (2/CU) x 256 thr, tile
//        64d x 32j, BK=128 LDS staging (transpose 4-way-conflict max),
//        b%8 XCD swizzle so same-b blocks share an L2.
//   k4 : C2Q = l2[i]*(E'@ (Qt/l1)), Q2C = l2[i]*(E'@Tt'); E' staged once in
//        LDS; Qt scaled by 1/l1[j] IN-REGISTER (no Qts buffer); B-operands
//        read from global (L2-hot); b%8 swizzle.
//
// l2 divides out of axis-1 softmax: S1 = E' * l2[i]/l1[j], so scaling the tiny
// Qt/Tt operands by 1/l1 and the k4 accumulators by l2[i] is exact algebra.
//
// Hard-won rules:
//  - LDS rows read as bf16x8 need 16B-multiple stride; row storage must hold
//    the full K-chunk (rounds 2-3 overflow bug).
//  - k3 MUST stage/transpose through LDS: global reads at 4KB lane-stride
//    amplify HBM traffic ~8x (round-7 regression).

#define LC 2048
#define LQ 256
#define DM 128
#define NEG_INF_F (-1e30f)

using bf16x8   = __attribute__((ext_vector_type(8))) __bf16;
using f32x4    = __attribute__((ext_vector_type(4))) float;
using ushort8  = __attribute__((ext_vector_type(8))) unsigned short;

__device__ __forceinline__ unsigned short f2bf(float x) {
    unsigned int u = __float_as_uint(x);
    u += 0x7fffu + ((u >> 16) & 1u);
    return (unsigned short)(u >> 16);
}
__device__ __forceinline__ float bf2f(unsigned short h) {
    return __uint_as_float(((unsigned int)h) << 16);
}
__device__ __forceinline__ f32x4 mfma16(bf16x8 a, bf16x8 b, f32x4 c) {
    return __builtin_amdgcn_mfma_f32_16x16x32_bf16(a, b, c, 0, 0, 0);
}

// ---------------------------------------------------------------------------
// Pre-Q: Qbf row-major bf16, Qt transposed bf16, rq = Q . w_q (atomic partial).
__global__ __launch_bounds__(256) void k_preQ(const float* __restrict__ Q,
        const float* __restrict__ w, unsigned short* __restrict__ Qbf,
        unsigned short* __restrict__ Qt, float* __restrict__ rq) {
    const int b = blockIdx.z, j0 = blockIdx.x * 64, d0 = blockIdx.y * 64;
    const int tid = threadIdx.x;
    __shared__ float tile[64][65];
    __shared__ float wq[128];
    if (tid < 128) wq[tid] = w[tid];
    __syncthreads();
    const int r = tid >> 2, c0 = (tid & 3) * 16;
    const float4* sp = (const float4*)(Q + (size_t)(b * LQ + j0 + r) * DM + d0 + c0);
    float v[16];
#pragma unroll
    for (int u = 0; u < 4; ++u) {
        float4 t = sp[u];
        v[4*u] = t.x; v[4*u+1] = t.y; v[4*u+2] = t.z; v[4*u+3] = t.w;
    }
    unsigned short ob[16];
    float p = 0.f;
#pragma unroll
    for (int u = 0; u < 16; ++u) {
        ob[u] = f2bf(v[u]);
        p += v[u] * wq[d0 + c0 + u];
        tile[r][c0 + u] = v[u];
    }
    ushort8* qb = (ushort8*)(Qbf + (size_t)(b * LQ + j0 + r) * DM + d0 + c0);
    qb[0] = *(ushort8*)&ob[0];
    qb[1] = *(ushort8*)&ob[8];
    p += __shfl_xor(p, 1);
    p += __shfl_xor(p, 2);
    if ((tid & 3) == 0) atomicAdd(&rq[b * LQ + j0 + r], p);
    __syncthreads();
    unsigned short o[16];
#pragma unroll
    for (int u = 0; u < 16; ++u) o[u] = f2bf(tile[c0 + u][r]);
    ushort8* dp = (ushort8*)(Qt + (size_t)(b * DM + d0 + r) * LQ + j0 + c0);
    dp[0] = *(ushort8*)&o[0];
    dp[1] = *(ushort8*)&o[8];
}

// ---------------------------------------------------------------------------
// K1: E' = exp(S)/l2, l2g, l1 atomics, Ct = C^T bf16.
// grid (32 itiles, 32 b), 256 thr. Tile 64(i) x 256(j); B-fragments read
// directly from global Qbf (L2-hot). Masks folded into rcs/rqs.
__global__ __launch_bounds__(256) void k1_scores(
    const float* __restrict__ C, const unsigned short* __restrict__ Qbf,
    const float* __restrict__ w, const float* __restrict__ bptr,
    const int* __restrict__ c_mask, const int* __restrict__ q_mask,
    const float* __restrict__ rq,
    unsigned short* __restrict__ E, unsigned short* __restrict__ Ct,
    float* __restrict__ l1g, float* __restrict__ l2g) {
    const int b = blockIdx.y;
    const int i0 = blockIdx.x * 64;
    const int tid = threadIdx.x;
    const int lane = tid & 63, wid = tid >> 6;
    const int quad = lane >> 4, l15 = lane & 15;

    __shared__ unsigned short Alds[64][136];  // (C*w_m) bf16
    __shared__ float wsm[256];                // [0:128)=w_c, [128:256)=w_m
    __shared__ float rcs[64], rqs[256], l2s[64];

    if (tid < 256) {
        wsm[tid] = w[128 + tid];
        const float qm = (float)q_mask[b * LQ + tid];
        rqs[tid] = (qm != 0.f) ? (rq[b * LQ + tid] + bptr[0]) : NEG_INF_F;
    }
    if (tid < 64) l2s[tid] = 0.f;
    __syncthreads();

    {   // stage A = C*w_m (bf16), rc = C . w_c (mask-folded), emit Ct = C^T
        const int r = tid >> 2, qq = tid & 3;
        const float4* cp = (const float4*)(C + (size_t)(b * LC + i0 + r) * DM + qq * 32);
        unsigned short* ctb = Ct + (size_t)b * DM * LC + i0 + r;
        float prc = 0.f;
#pragma unroll
        for (int u = 0; u < 8; ++u) {
            float4 v = cp[u];
            const int c0 = qq * 32 + u * 4;
            prc += v.x * wsm[c0] + v.y * wsm[c0 + 1] + v.z * wsm[c0 + 2] + v.w * wsm[c0 + 3];
            Alds[r][c0 + 0] = f2bf(v.x * wsm[128 + c0]);
            Alds[r][c0 + 1] = f2bf(v.y * wsm[129 + c0]);
            Alds[r][c0 + 2] = f2bf(v.z * wsm[130 + c0]);
            Alds[r][c0 + 3] = f2bf(v.w * wsm[131 + c0]);
            ctb[(size_t)(c0 + 0) * LC] = f2bf(v.x);
            ctb[(size_t)(c0 + 1) * LC] = f2bf(v.y);
            ctb[(size_t)(c0 + 2) * LC] = f2bf(v.z);
            ctb[(size_t)(c0 + 3) * LC] = f2bf(v.w);
        }
        prc += __shfl_xor(prc, 1);
        prc += __shfl_xor(prc, 2);
        if (qq == 0) {
            const float cmv = (float)c_mask[b * LC + i0 + r];
            rcs[r] = (cmv != 0.f) ? prc : NEG_INF_F;
        }
    }
    __syncthreads();

    const int n_base = wid * 64;
    const unsigned short* qbase = Qbf + (size_t)b * LQ * DM;
    const f32x4 z4 = {0.f, 0.f, 0.f, 0.f};
    f32x4 acc[4][4];
#pragma unroll
    for (int mt = 0; mt < 4; ++mt)
#pragma unroll
        for (int nt = 0; nt < 4; ++nt) acc[mt][nt] = z4;

#pragma unroll
    for (int kc = 0; kc < 4; ++kc) {
        const int ko = kc * 32 + quad * 8;
        bf16x8 af[4], bfr[4];
#pragma unroll
        for (int mt = 0; mt < 4; ++mt)
            af[mt] = *(const bf16x8*)&Alds[mt * 16 + l15][ko];
#pragma unroll
        for (int nt = 0; nt < 4; ++nt)
            bfr[nt] = *(const bf16x8*)(qbase + (size_t)(n_base + nt * 16 + l15) * DM + ko);
#pragma unroll
        for (int mt = 0; mt < 4; ++mt)
#pragma unroll
            for (int nt = 0; nt < 4; ++nt)
                acc[mt][nt] = mfma16(af[mt], bfr[nt], acc[mt][nt]);
    }

    float colsum[4] = {0.f, 0.f, 0.f, 0.f};
#pragma unroll
    for (int mt = 0; mt < 4; ++mt) {
#pragma unroll
        for (int reg = 0; reg < 4; ++reg) {
            const int m = mt * 16 + quad * 4 + reg;
            float rowsum = 0.f;
#pragma unroll
            for (int nt = 0; nt < 4; ++nt) {
                const int n = n_base + nt * 16 + l15;
                const float s = acc[mt][nt][reg] + rcs[m] + rqs[n];
                const float e = __expf(s);
                acc[mt][nt][reg] = e;      // keep raw e in regs
                rowsum += e;
                colsum[nt] += e;
            }
            rowsum += __shfl_xor(rowsum, 1);
            rowsum += __shfl_xor(rowsum, 2);
            rowsum += __shfl_xor(rowsum, 4);
            rowsum += __shfl_xor(rowsum, 8);
            if (l15 == 0) atomicAdd(&l2s[m], rowsum);
        }
    }
#pragma unroll
    for (int nt = 0; nt < 4; ++nt) {
        float v = colsum[nt];
        v += __shfl_xor(v, 16);
        v += __shfl_xor(v, 32);
        if (quad == 0) atomicAdd(&l1g[b * LQ + n_base + nt * 16 + l15], v);
    }
    __syncthreads();
    if (tid < 64) l2g[b * LC + i0 + tid] = l2s[tid];

    // E' = e / l2[i], bf16, scalar stores (32B chunks per 16-lane group)
#pragma unroll
    for (int mt = 0; mt < 4; ++mt) {
#pragma unroll
        for (int reg = 0; reg < 4; ++reg) {
            const int m = mt * 16 + quad * 4 + reg;
            const float rl = 1.0f / l2s[m];
            unsigned short* erow = E + (size_t)(b * LC + i0 + m) * LQ;
#pragma unroll
            for (int nt = 0; nt < 4; ++nt) {
                const int n = n_base + nt * 16 + l15;
                erow[n] = f2bf(acc[mt][nt][reg] * rl);
            }
        }
    }
}

// ---------------------------------------------------------------------------
// K3: Tt'[d][j] = (sum_i Ct[d][i]*E'[i][j]) / l1[j]. 1D grid 512 blocks
// (2/CU -> cross-block barrier overlap), 256 thr (4 waves), tile 64d x 32j,
// K=2048 in BK=128 chunks. id%8 == b%8 keeps same-b blocks on one XCD L2.
__global__ __launch_bounds__(256) void k3_Tt(
    const unsigned short* __restrict__ E, const unsigned short* __restrict__ Ct,
    const float* __restrict__ l1g, unsigned short* __restrict__ Tt) {
    const int id = blockIdx.x;
    const int rest = id >> 3;
    const int jt = rest & 7;              // 8 tiles of 32 j
    const int dt = (rest >> 3) & 1;       // 2 tiles of 64 d
    const int b  = ((rest >> 4) << 3) | (id & 7);
    const int j0 = jt * 32, d0 = dt * 64;
    const int tid = threadIdx.x;
    const int lane = tid & 63, wid = tid >> 6;
    const int quad = lane >> 4, l15 = lane & 15;
    const int m_base = wid * 16;

    __shared__ unsigned short Ab[64][136];   // Ct rows (d-major, 128 i + pad)
    __shared__ unsigned short Bb[32][136];   // E'^T (j-major, 128 i + pad)
    __shared__ float rl1s[32];
    if (tid < 32) rl1s[tid] = 1.0f / l1g[b * LQ + j0 + tid];

    const f32x4 z4 = {0.f, 0.f, 0.f, 0.f};
    f32x4 acc[2] = {z4, z4};

    for (int it = 0; it < 16; ++it) {
        const int ic = it * 128;
        __syncthreads();
        {   // stage Ct chunk [64 d][128 i] (vectorized copy, 64B/thread)
            const int r = tid >> 2, q = (tid & 3) * 32;
            const ushort8* cp = (const ushort8*)(Ct + (size_t)(b * DM + d0 + r) * LC + ic + q);
            *(ushort8*)&Ab[r][q]      = cp[0];
            *(ushort8*)&Ab[r][q + 8]  = cp[1];
            *(ushort8*)&Ab[r][q + 16] = cp[2];
            *(ushort8*)&Ab[r][q + 24] = cp[3];
        }
        {   // stage E'^T chunk [128 i][32 j] (vec load, scalar transpose writes)
            const int il = tid >> 1, sg = (tid & 1) * 16;
            const ushort8* ep = (const ushort8*)(E + (size_t)(b * LC + ic + il) * LQ + j0 + sg);
            ushort8 e0 = ep[0], e1 = ep[1];
#pragma unroll
            for (int u = 0; u < 8; ++u) Bb[sg + u][il] = e0[u];
#pragma unroll
            for (int u = 0; u < 8; ++u) Bb[sg + 8 + u][il] = e1[u];
        }
        __syncthreads();
#pragma unroll
        for (int kk = 0; kk < 4; ++kk) {
            const int ko = kk * 32 + quad * 8;
            bf16x8 af  = *(const bf16x8*)&Ab[m_base + l15][ko];
            bf16x8 b0f = *(const bf16x8*)&Bb[l15][ko];
            bf16x8 b1f = *(const bf16x8*)&Bb[16 + l15][ko];
            acc[0] = mfma16(af, b0f, acc[0]);
            acc[1] = mfma16(af, b1f, acc[1]);
        }
    }
#pragma unroll
    for (int nt = 0; nt < 2; ++nt)
#pragma unroll
        for (int reg = 0; reg < 4; ++reg) {
            const int dd = d0 + m_base + quad * 4 + reg;
            const int jl = nt * 16 + l15;
            Tt[(size_t)(b * DM + dd) * LQ + j0 + jl] = f2bf(acc[nt][reg] * rl1s[jl]);
        }
}

// ---------------------------------------------------------------------------
// K4: acc1 = E'@(Qt/l1), acc2 = E'@Tt'; out = [C, l2*a1, C*l2*a1, C*l2*a2].
// 1D grid 1024 blocks (b%8 XCD class), 256 thr (4 waves), tile 64i x 128d.
// E' staged once in LDS; Qt B-frags scaled by 1/l1[j] in-register (Qts
// buffer eliminated); Tt read directly from global (L2-hot).
__global__ __launch_bounds__(256) void k4_out(
    const unsigned short* __restrict__ E, const float* __restrict__ C,
    const unsigned short* __restrict__ Qt, const unsigned short* __restrict__ Tt,
    const float* __restrict__ l1g, const float* __restrict__ l2g,
    float* __restrict__ out) {
    const int id = blockIdx.x;
    const int b = (id & 7) | ((id >> 8) << 3);
    const int i0 = ((id >> 3) & 31) * 64;
    const int tid = threadIdx.x;
    const int lane = tid & 63, wid = tid >> 6;
    const int quad = lane >> 4, l15 = lane & 15;
    const int n_base = wid * 32;

    __shared__ unsigned short Aq[64][264];   // E' full-j tile (256 + 8 pad)
    __shared__ float l2s[64];
    __shared__ float rl1s[256];
    if (tid < 64) l2s[tid] = l2g[b * LC + i0 + tid];
    rl1s[tid] = 1.0f / l1g[b * LQ + tid];

    {   // stage E' tile (64 rows x 256 j), coalesced, once
        const int r = tid >> 2, c0 = (tid & 3) * 64;
        const ushort8* ep = (const ushort8*)(E + (size_t)(b * LC + i0 + r) * LQ + c0);
#pragma unroll
        for (int u = 0; u < 8; ++u) *(ushort8*)&Aq[r][c0 + u * 8] = ep[u];
    }
    __syncthreads();

    const unsigned short* qtb = Qt + (size_t)b * DM * LQ;
    const unsigned short* ttb = Tt + (size_t)b * DM * LQ;
    const f32x4 z4 = {0.f, 0.f, 0.f, 0.f};
    f32x4 acc1[4][2], acc2[4][2];
#pragma unroll
    for (int mt = 0; mt < 4; ++mt)
#pragma unroll
        for (int nt = 0; nt < 2; ++nt) { acc1[mt][nt] = z4; acc2[mt][nt] = z4; }

#pragma unroll 2
    for (int ks = 0; ks < 8; ++ks) {
        const int ko = ks * 32 + quad * 8;
        bf16x8 a[4], bq[2], bt[2];
#pragma unroll
        for (int mt = 0; mt < 4; ++mt)
            a[mt] = *(const bf16x8*)&Aq[mt * 16 + l15][ko];
#pragma unroll
        for (int nt = 0; nt < 2; ++nt) {
            const size_t roff = (size_t)(n_base + nt * 16 + l15) * LQ + ko;
            const ushort8 qr = *(const ushort8*)(qtb + roff);
            unsigned short qs[8];
#pragma unroll
            for (int e = 0; e < 8; ++e)
                qs[e] = f2bf(bf2f(qr[e]) * rl1s[ko + e]);
            bq[nt] = *(const bf16x8*)qs;
            bt[nt] = *(const bf16x8*)(ttb + roff);
        }
#pragma unroll
        for (int mt = 0; mt < 4; ++mt)
#pragma unroll
            for (int nt = 0; nt < 2; ++nt) {
                acc1[mt][nt] = mfma16(a[mt], bq[nt], acc1[mt][nt]);
                acc2[mt][nt] = mfma16(a[mt], bt[nt], acc2[mt][nt]);
            }
    }

#pragma unroll
    for (int mt = 0; mt < 4; ++mt)
#pragma unroll
        for (int reg = 0; reg < 4; ++reg) {
            const int il = mt * 16 + quad * 4 + reg;
            const int i = i0 + il;
            const float l2v = l2s[il];
            const size_t rb = (size_t)(b * LC + i) * 512;
            const float* crow = C + (size_t)(b * LC + i) * DM;
#pragma unroll
            for (int nt = 0; nt < 2; ++nt) {
                const int d = n_base + nt * 16 + l15;
                const float c = crow[d];
                const float v1 = acc1[mt][nt][reg] * l2v;
                const float v2 = acc2[mt][nt][reg] * l2v;
                out[rb + d] = c;
                out[rb + 128 + d] = v1;
                out[rb + 256 + d] = c * v1;
                out[rb + 384 + d] = c * v2;
            }
        }
}

// ---------------------------------------------------------------------------
extern "C" void kernel_launch(void* const* d_in, const int* in_sizes, int n_in,
                              void* d_out, int out_size, void* d_ws, size_t ws_size,
                              hipStream_t stream) {
    const float* C = (const float*)d_in[0];
    const float* Q = (const float*)d_in[1];
    const float* w = (const float*)d_in[2];
    const float* bp = (const float*)d_in[3];
    const int* cm = (const int*)d_in[4];
    const int* qm = (const int*)d_in[5];
    float* out = (float*)d_out;

    char* ws = (char*)d_ws;
    // E 32MB | Ct 16MB | Qbf 2MB | Qt 2MB | (gap 2MB) | Tt 2MB | l2g 256KB |
    // rq 32KB | l1 32KB
    unsigned short* E   = (unsigned short*)(ws);
    unsigned short* Ct  = (unsigned short*)(ws + 33554432);
    unsigned short* Qbf = (unsigned short*)(ws + 50331648);
    unsigned short* Qt  = (unsigned short*)(ws + 52428800);
    unsigned short* Tt  = (unsigned short*)(ws + 56623104);
    float*          l2g = (float*)(ws + 58720256);
    float*          rq  = (float*)(ws + 58982400);
    float*          l1  = (float*)(ws + 59015168);

    hipMemsetAsync(ws + 58982400, 0, 65536, stream);  // zero rq + l1

    k_preQ<<<dim3(4, 2, 32), 256, 0, stream>>>(Q, w, Qbf, Qt, rq);
    k1_scores<<<dim3(32, 32), 256, 0, stream>>>(C, Qbf, w, bp, cm, qm, rq, E, Ct, l1, l2g);
    k3_Tt<<<dim3(512), 256, 0, stream>>>(E, Ct, l1, Tt);
    k4_out<<<dim3(1024), 256, 0, stream>>>(E, C, Qt, Tt, l1, l2g, out);
}